// Round 7
// baseline (211.407 us; speedup 1.0000x reference)
//
#include <hip/hip_runtime.h>
#include <math.h>

// B=32, C=256, H=W=56; emb: Ce=128 @28x28; inference: 1x112x112.
// out = sigmoid(main) * (mask*weight + 1)
// Algebra: mean_o(1x1conv) = dot(emb, colmean W) + mean(b); upsample is linear
// -> reduce channels at 28x28. Min-max norm is invariant to positive scale AND
// shift -> drop the 1/256 and the bias: e_red = dot(emb, colsum W).
// dur_us includes ~121us of harness fill/copy reset; controllable part ~84us.

#define HW_E 784
#define HW_O 3136
#define CE   128
#define CO   256
#define NB   32

typedef float f4 __attribute__((ext_vector_type(4)));

// fast sigmoid: v_exp_f32 (2^x) + v_rcp_f32, ~3 VALU ops vs ~17 for expf+div
#if __has_builtin(__builtin_amdgcn_exp2f)
__device__ inline float fexp2(float x) { return __builtin_amdgcn_exp2f(x); }
#else
__device__ inline float fexp2(float x) { return exp2f(x); }
#endif
#if __has_builtin(__builtin_amdgcn_rcpf)
__device__ inline float frcp(float x) { return __builtin_amdgcn_rcpf(x); }
#else
__device__ inline float frcp(float x) { return 1.0f / x; }
#endif
#define LOG2E 1.4426950408889634f
__device__ inline float fsig(float x) { return frcp(1.0f + fexp2(-LOG2E * x)); }

// ---- block min/max reduce for 1024 threads (16 waves) -----------------------
__device__ inline void bmm(float lmin, float lmax, float* red, int t,
                           float& mn, float& mx) {
    __syncthreads();                       // protect red[] reuse + order sM writes
    #pragma unroll
    for (int off = 32; off; off >>= 1) {
        lmin = fminf(lmin, __shfl_down(lmin, off, 64));
        lmax = fmaxf(lmax, __shfl_down(lmax, off, 64));
    }
    if ((t & 63) == 0) { red[t >> 6] = lmin; red[16 + (t >> 6)] = lmax; }
    __syncthreads();
    if (t == 0) {
        float a = red[0], b = red[16];
        #pragma unroll
        for (int i = 1; i < 16; ++i) { a = fminf(a, red[i]); b = fmaxf(b, red[16 + i]); }
        red[0] = a; red[16] = b;
    }
    __syncthreads();
    mn = red[0]; mx = red[16];
}

// ---- kernel 1 (fused): per-sample  W-colsum -> chan-dot -> mask -> s --------
// 32 blocks x 1024 threads, one block per sample.
__global__ __launch_bounds__(1024) void k_premask(const float* __restrict__ emb,
                                                  const float* __restrict__ W,
                                                  const float* __restrict__ infx,
                                                  const float* __restrict__ wscalar,
                                                  float* __restrict__ sout) {
    __shared__ float swp[8][CE];
    __shared__ float swb[CE];
    __shared__ float sE[HW_E];
    __shared__ float sM[HW_O];
    __shared__ float red[32];
    const int n = blockIdx.x;
    const int t = threadIdx.x;

    // stage A: colsum of W -> swb[128]. thread t = (o-group t>>7, channel t&127)
    {
        const int c  = t & 127;
        const int og = t >> 7;                         // 0..7, 32 o's each
        const float* wp = W + (size_t)(og * 32) * CE + c;
        float a = 0.f;
        #pragma unroll
        for (int k = 0; k < 32; ++k) a += wp[(size_t)k * CE];   // contiguous across c
        swp[og][c] = a;
    }
    __syncthreads();
    if (t < CE) {
        float a = 0.f;
        #pragma unroll
        for (int g = 0; g < 8; ++g) a += swp[g][t];
        swb[t] = a;
    }
    __syncthreads();

    // stage B: e_red at 28x28: threads 0..783 each do a 128-channel dot
    if (t < HW_E) {
        const float* base = emb + (size_t)n * CE * HW_E + t;
        float acc = 0.f;
        #pragma unroll 8
        for (int c = 0; c < CE; ++c) acc += base[(size_t)c * HW_E] * swb[c];
        sE[t] = acc;
    }
    __syncthreads();

    // phase 1: 28->56 bilinear (align_corners=False); min/max
    float lmin = 1e30f, lmax = -1e30f;
    for (int p = t; p < HW_O; p += 1024) {
        int oh = p / 56, ow = p % 56;
        float ys = fminf(fmaxf(0.5f * oh - 0.25f, 0.f), 27.f);
        float xs = fminf(fmaxf(0.5f * ow - 0.25f, 0.f), 27.f);
        int y0 = (int)ys, x0 = (int)xs;
        int y1 = min(y0 + 1, 27), x1 = min(x0 + 1, 27);
        float wy = ys - (float)y0, wx = xs - (float)x0;
        float v00 = sE[y0 * 28 + x0], v01 = sE[y0 * 28 + x1];
        float v10 = sE[y1 * 28 + x0], v11 = sE[y1 * 28 + x1];
        float r0 = v00 * (1.f - wy) + v10 * wy;
        float r1 = v01 * (1.f - wy) + v11 * wy;
        float m  = r0 * (1.f - wx) + r1 * wx;
        sM[p] = m;
        lmin = fminf(lmin, m); lmax = fmaxf(lmax, m);
    }
    float mn1, mx1;
    bmm(lmin, lmax, red, t, mn1, mx1);
    float inv1 = 1.f / (mx1 - mn1);

    // phase 2: * bilinear-down(inference, align_corners=True); min/max
    const float step = 111.0f / 55.0f;
    const float* xin = infx + (size_t)n * 112 * 112;
    float lmin2 = 1e30f, lmax2 = -1e30f;
    for (int p = t; p < HW_O; p += 1024) {
        int oh = p / 56, ow = p % 56;
        float ys = step * (float)oh, xs = step * (float)ow;
        int y0 = (int)ys, x0 = (int)xs;
        int y1 = min(y0 + 1, 111), x1 = min(x0 + 1, 111);
        float wy = ys - (float)y0, wx = xs - (float)x0;
        float v00 = xin[y0 * 112 + x0], v01 = xin[y0 * 112 + x1];
        float v10 = xin[y1 * 112 + x0], v11 = xin[y1 * 112 + x1];
        float r0 = v00 * (1.f - wy) + v10 * wy;
        float r1 = v01 * (1.f - wy) + v11 * wy;
        float inf = r0 * (1.f - wx) + r1 * wx;
        float p2 = (sM[p] - mn1) * inv1 * inf;
        sM[p] = p2;
        lmin2 = fminf(lmin2, p2); lmax2 = fmaxf(lmax2, p2);
    }
    float mn2, mx2;
    bmm(lmin2, lmax2, red, t, mn2, mx2);
    float inv2 = 1.f / (mx2 - mn2);
    float wgt = wscalar[0];

    for (int p = t; p < HW_O; p += 1024)
        sout[n * HW_O + p] = (sM[p] - mn2) * inv2 * wgt + 1.0f;
}

// ---- kernel 2: out = sigmoid(main) * s — the roofline kernel ----------------
// One-shot: 4 quads/thread, all 8 loads issued up front; nontemporal streams;
// cheap sigmoid so VALU never caps BW.
__global__ __launch_bounds__(256, 8) void k_main(const float* __restrict__ x,
                                                 const float* __restrict__ s,
                                                 float* __restrict__ out, int total4) {
    const f4* x4 = (const f4*)x;
    const f4* s4 = (const f4*)s;
    f4* o4 = (f4*)out;
    const int q0 = blockIdx.x * 1024 + threadIdx.x;

    int q[4] = { q0, q0 + 256, q0 + 512, q0 + 768 };
    f4 v[4], sv[4];
    #pragma unroll
    for (int j = 0; j < 4; ++j)
        if (q[j] < total4) v[j] = __builtin_nontemporal_load(&x4[q[j]]);
    #pragma unroll
    for (int j = 0; j < 4; ++j)
        if (q[j] < total4) {
            int hwq = q[j] % (HW_O / 4);               // 784 quads per channel image
            int n   = q[j] / ((HW_O / 4) * CO);        // / 200704
            sv[j] = s4[n * (HW_O / 4) + hwq];
        }
    #pragma unroll
    for (int j = 0; j < 4; ++j)
        if (q[j] < total4) {
            f4 r;
            r.x = sv[j].x * fsig(v[j].x);
            r.y = sv[j].y * fsig(v[j].y);
            r.z = sv[j].z * fsig(v[j].z);
            r.w = sv[j].w * fsig(v[j].w);
            __builtin_nontemporal_store(r, &o4[q[j]]);
        }
}

extern "C" void kernel_launch(void* const* d_in, const int* in_sizes, int n_in,
                              void* d_out, int out_size, void* d_ws, size_t ws_size,
                              hipStream_t stream) {
    const float* main_in = (const float*)d_in[0];   // [32,256,56,56]
    const float* emb_in  = (const float*)d_in[1];   // [32,128,28,28]
    const float* inf_in  = (const float*)d_in[2];   // [32,1,112,112]
    const float* conv_w  = (const float*)d_in[3];   // [256,128]
    const float* weight  = (const float*)d_in[5];   // [1]
    float* out = (float*)d_out;
    float* ws  = (float*)d_ws;                      // s = mask*w+1, 32*3136 floats

    k_premask<<<NB, 1024, 0, stream>>>(emb_in, conv_w, inf_in, weight, ws);

    int total4 = out_size / 4;                      // 6,422,528
    int blocks = (total4 + 1023) / 1024;            // 6272
    k_main<<<blocks, 256, 0, stream>>>(main_in, ws, out, total4);
}

// Round 8
// 201.478 us; speedup vs baseline: 1.0493x; 1.0493x over previous
//
#include <hip/hip_runtime.h>
#include <math.h>

// B=32, C=256, H=W=56; emb: Ce=128 @28x28; inference: 1x112x112.
// out = sigmoid(main) * (mask*weight + 1)
// Algebra: mean_o(1x1conv) = dot(emb, colmean W) + mean(b); upsample is linear
// -> reduce channels at 28x28. Min-max norm is invariant to positive scale AND
// shift -> drop the 1/256 and the bias: e_red = dot(emb, colsum W).
// NOTE: dur_us includes ~122us of harness fill/copy reset (fixed floor).
// R7 lesson: fusing ered into the 32-block mask kernel capped the emb read at
// 32 CUs (~768 GB/s) — keep ered on 784 blocks.

#define HW_E 784
#define HW_O 3136
#define CE   128
#define CO   256
#define NB   32
#define KS   8            // channel split parts
#define CPP  (CE / KS)    // 16 channels per part
#define NPE  (NB * HW_E)  // 25088 outputs per part

#define ERED_OFF 0
#define S_OFF    (KS * NPE)   // 200704 floats

typedef float f4 __attribute__((ext_vector_type(4)));

// fast sigmoid: v_exp_f32 (2^x) + v_rcp_f32, ~3 VALU ops vs ~17 for expf+div
#if __has_builtin(__builtin_amdgcn_exp2f)
__device__ inline float fexp2(float x) { return __builtin_amdgcn_exp2f(x); }
#else
__device__ inline float fexp2(float x) { return exp2f(x); }
#endif
#if __has_builtin(__builtin_amdgcn_rcpf)
__device__ inline float frcp(float x) { return __builtin_amdgcn_rcpf(x); }
#else
__device__ inline float frcp(float x) { return 1.0f / x; }
#endif
#define LOG2E 1.4426950408889634f
__device__ inline float fsig(float x) { return frcp(1.0f + fexp2(-LOG2E * x)); }

// ---- kernel 1: e_red partials; each block computes its own 16-wide W colsum --
__global__ __launch_bounds__(256) void k_ered(const float* __restrict__ emb,
                                              const float* __restrict__ W,
                                              float* __restrict__ ered) {
    __shared__ float swp[4][CPP];
    __shared__ float swb[CPP];
    const int t   = threadIdx.x;
    const int gid = blockIdx.x * 256 + t;
    const int part = gid / NPE;            // uniform per block (NPE % 256 == 0)
    const int cb   = part * CPP;

    // colsum of W for channels [cb, cb+16): thread t -> channel j=t&15, o-chunk t>>4
    {
        const int j  = t & 15;
        const int oc = t >> 4;             // 0..15, each covers 16 o's
        const float* wp = W + (size_t)(oc * 16) * CE + cb + j;
        float a = 0.f;
        #pragma unroll
        for (int k = 0; k < 16; ++k) a += wp[(size_t)k * CE];
        a += __shfl_xor(a, 16, 64);        // reduce o-chunks within wave
        a += __shfl_xor(a, 32, 64);
        if ((t & 63) < CPP) swp[t >> 6][j] = a;
    }
    __syncthreads();
    if (t < CPP) swb[t] = swp[0][t] + swp[1][t] + swp[2][t] + swp[3][t];
    __syncthreads();

    const int local = gid - part * NPE;
    const int n = local / HW_E;
    const int p = local - n * HW_E;
    const float* base = emb + ((size_t)n * CE + cb) * HW_E + p;
    float acc = 0.f;
    #pragma unroll
    for (int c = 0; c < CPP; ++c) acc += base[(size_t)c * HW_E] * swb[c];
    ered[gid] = acc;
}

// ---- block min/max reduce for 1024 threads (16 waves) -----------------------
__device__ inline void bmm(float lmin, float lmax, float* red, int t,
                           float& mn, float& mx) {
    __syncthreads();                       // protect red[] reuse + order sM writes
    #pragma unroll
    for (int off = 32; off; off >>= 1) {
        lmin = fminf(lmin, __shfl_down(lmin, off, 64));
        lmax = fmaxf(lmax, __shfl_down(lmax, off, 64));
    }
    if ((t & 63) == 0) { red[t >> 6] = lmin; red[16 + (t >> 6)] = lmax; }
    __syncthreads();
    if (t == 0) {
        float a = red[0], b = red[16];
        #pragma unroll
        for (int i = 1; i < 16; ++i) { a = fminf(a, red[i]); b = fmaxf(b, red[16 + i]); }
        red[0] = a; red[16] = b;
    }
    __syncthreads();
    mn = red[0]; mx = red[16];
}

// ---- kernel 2: per-sample mask -> s = mask*weight + 1 -----------------------
__global__ __launch_bounds__(1024) void k_mask(const float* __restrict__ infx,
                                               const float* __restrict__ ered,
                                               const float* __restrict__ wscalar,
                                               float* __restrict__ sout) {
    __shared__ float sE[HW_E];
    __shared__ float sM[HW_O];
    __shared__ float red[32];
    const int n = blockIdx.x;
    const int t = threadIdx.x;

    if (t < HW_E) {
        float v = 0.f;
        #pragma unroll
        for (int k = 0; k < KS; ++k) v += ered[k * NPE + n * HW_E + t];
        sE[t] = v;
    }
    __syncthreads();

    // phase 1: 28->56 bilinear (align_corners=False); min/max
    float lmin = 1e30f, lmax = -1e30f;
    for (int p = t; p < HW_O; p += 1024) {
        int oh = p / 56, ow = p % 56;
        float ys = fminf(fmaxf(0.5f * oh - 0.25f, 0.f), 27.f);
        float xs = fminf(fmaxf(0.5f * ow - 0.25f, 0.f), 27.f);
        int y0 = (int)ys, x0 = (int)xs;
        int y1 = min(y0 + 1, 27), x1 = min(x0 + 1, 27);
        float wy = ys - (float)y0, wx = xs - (float)x0;
        float v00 = sE[y0 * 28 + x0], v01 = sE[y0 * 28 + x1];
        float v10 = sE[y1 * 28 + x0], v11 = sE[y1 * 28 + x1];
        float r0 = v00 * (1.f - wy) + v10 * wy;
        float r1 = v01 * (1.f - wy) + v11 * wy;
        float m  = r0 * (1.f - wx) + r1 * wx;
        sM[p] = m;
        lmin = fminf(lmin, m); lmax = fmaxf(lmax, m);
    }
    float mn1, mx1;
    bmm(lmin, lmax, red, t, mn1, mx1);
    float inv1 = 1.f / (mx1 - mn1);

    // phase 2: * bilinear-down(inference, align_corners=True); min/max
    const float step = 111.0f / 55.0f;
    const float* xin = infx + (size_t)n * 112 * 112;
    float lmin2 = 1e30f, lmax2 = -1e30f;
    for (int p = t; p < HW_O; p += 1024) {
        int oh = p / 56, ow = p % 56;
        float ys = step * (float)oh, xs = step * (float)ow;
        int y0 = (int)ys, x0 = (int)xs;
        int y1 = min(y0 + 1, 111), x1 = min(x0 + 1, 111);
        float wy = ys - (float)y0, wx = xs - (float)x0;
        float v00 = xin[y0 * 112 + x0], v01 = xin[y0 * 112 + x1];
        float v10 = xin[y1 * 112 + x0], v11 = xin[y1 * 112 + x1];
        float r0 = v00 * (1.f - wy) + v10 * wy;
        float r1 = v01 * (1.f - wy) + v11 * wy;
        float inf = r0 * (1.f - wx) + r1 * wx;
        float p2 = (sM[p] - mn1) * inv1 * inf;
        sM[p] = p2;
        lmin2 = fminf(lmin2, p2); lmax2 = fmaxf(lmax2, p2);
    }
    float mn2, mx2;
    bmm(lmin2, lmax2, red, t, mn2, mx2);
    float inv2 = 1.f / (mx2 - mn2);
    float wgt = wscalar[0];

    for (int p = t; p < HW_O; p += 1024)
        sout[n * HW_O + p] = (sM[p] - mn2) * inv2 * wgt + 1.0f;
}

// ---- kernel 3: out = sigmoid(main) * s — the roofline kernel ----------------
// 6272 blocks x 256 threads x 4 quads = exactly total4: no bounds guards.
// All 8 loads issued up front; nontemporal big streams; cheap sigmoid.
__global__ __launch_bounds__(256, 8) void k_main(const float* __restrict__ x,
                                                 const float* __restrict__ s,
                                                 float* __restrict__ out) {
    const f4* x4 = (const f4*)x;
    const f4* s4 = (const f4*)s;
    f4* o4 = (f4*)out;
    const int q0 = blockIdx.x * 1024 + threadIdx.x;

    f4 v[4], sv[4];
    #pragma unroll
    for (int j = 0; j < 4; ++j)
        v[j] = __builtin_nontemporal_load(&x4[q0 + j * 256]);
    #pragma unroll
    for (int j = 0; j < 4; ++j) {
        int q   = q0 + j * 256;
        int hwq = q % (HW_O / 4);                  // 784 quads per channel image
        int n   = q / ((HW_O / 4) * CO);           // / 200704
        sv[j] = s4[n * (HW_O / 4) + hwq];
    }
    #pragma unroll
    for (int j = 0; j < 4; ++j) {
        f4 r;
        r.x = sv[j].x * fsig(v[j].x);
        r.y = sv[j].y * fsig(v[j].y);
        r.z = sv[j].z * fsig(v[j].z);
        r.w = sv[j].w * fsig(v[j].w);
        __builtin_nontemporal_store(r, &o4[q0 + j * 256]);
    }
}

extern "C" void kernel_launch(void* const* d_in, const int* in_sizes, int n_in,
                              void* d_out, int out_size, void* d_ws, size_t ws_size,
                              hipStream_t stream) {
    const float* main_in = (const float*)d_in[0];   // [32,256,56,56]
    const float* emb_in  = (const float*)d_in[1];   // [32,128,28,28]
    const float* inf_in  = (const float*)d_in[2];   // [32,1,112,112]
    const float* conv_w  = (const float*)d_in[3];   // [256,128]
    const float* weight  = (const float*)d_in[5];   // [1]
    float* out = (float*)d_out;
    float* ws  = (float*)d_ws;

    k_ered<<<KS * NPE / 256, 256, 0, stream>>>(emb_in, conv_w, ws + ERED_OFF);
    k_mask<<<NB, 1024, 0, stream>>>(inf_in, ws + ERED_OFF, weight, ws + S_OFF);

    // 6272 blocks * 1024 quads == 6,422,528 == out_size/4 exactly
    k_main<<<6272, 256, 0, stream>>>(main_in, ws + S_OFF, out);
}